// Round 1
// 938.285 us; speedup vs baseline: 1.2247x; 1.2247x over previous
//
#include <hip/hip_runtime.h>
#include <math.h>

// Problem constants (from reference)
#define NB   512    // batch
#define NQ   64     // queries
#define NCC  1000   // candidates
#define EE   128    // embed
#define HH   8      // heads
#define HDD  16     // head dim
#define NL   3      // GAT layers
#define DD   4      // cluster depth
#define KP   136    // LDS pitch (ushort) for compat K hi/lo staging
#define XP   136    // LDS pitch (ushort) for gat [64][128] bufs
#define VP   72     // LDS pitch (ushort) for gat V^T [128][64]

typedef __bf16 bf16x8 __attribute__((ext_vector_type(8)));
typedef unsigned short u16x8 __attribute__((ext_vector_type(8)));
typedef unsigned short u16x4 __attribute__((ext_vector_type(4)));
typedef unsigned int   u32x4 __attribute__((ext_vector_type(4)));
typedef float f32x4  __attribute__((ext_vector_type(4)));
typedef float f32x16 __attribute__((ext_vector_type(16)));

__device__ __forceinline__ unsigned short f2bf(float x) {
  union { float f; unsigned u; } v; v.f = x;
  unsigned r = (v.u + 0x7fffu + ((v.u >> 16) & 1u)) >> 16;
  return (unsigned short)r;
}
__device__ __forceinline__ float bf2f(unsigned short h) {
  union { unsigned u; float f; } v; v.u = ((unsigned)h) << 16;
  return v.f;
}
__device__ __forceinline__ bf16x8 ld8(const unsigned short* p) {
  return __builtin_bit_cast(bf16x8, *(const u16x8*)p);
}

// ---------------------------------------------------------------------------
// Kernel 0: weight prep. Transpose + bf16 hi/lo split for all 14 matrices:
//   m = l*4 + {0:Wq,1:Wk,2:Wv,3:Wo} for l in 0..2, m=12: final Wq, m=13: final Wk.
// Output layout per mat: [n*128 + k] so MFMA B-fragments read 8 contiguous k's.
// m=13 region doubles as the compat kernel's wkt_hi/wkt_lo.
// ---------------------------------------------------------------------------
__global__ __launch_bounds__(256) void wprep_kernel(
    const float* __restrict__ gWq, const float* __restrict__ gWk,
    const float* __restrict__ gWv, const float* __restrict__ gWo,
    const float* __restrict__ Wq,  const float* __restrict__ Wk,
    unsigned short* __restrict__ gwt_hi, unsigned short* __restrict__ gwt_lo)
{
  const int idx = blockIdx.x * 256 + threadIdx.x;   // 896 blocks -> 14*16384
  const int m = idx >> 14;
  const int r = idx & 16383;
  const int k = r >> 7, n = r & 127;
  const float* src;
  if (m < 12) {
    const int l = m >> 2, w = m & 3;
    src = (w == 0 ? gWq : w == 1 ? gWk : w == 2 ? gWv : gWo) + l * 16384;
  } else if (m == 12) src = Wq;
  else                src = Wk;
  const float v = src[k * EE + n];
  const unsigned short h = f2bf(v);
  gwt_hi[(size_t)m * 16384 + n * EE + k] = h;
  gwt_lo[(size_t)m * 16384 + n * EE + k] = f2bf(v - bf2f(h));
}

// ---------------------------------------------------------------------------
// Kernel 1: MFMA GAT (3 fused MHA layers) + final query projection.
// One block per batch, 512 threads = 8 waves.
//  P1: Q,K,V = X@W + b  via 16x16x32 bf16 hi/lo split MFMA.
//      wave w: m-tile = w>>1 (16 rows), n-half = w&1 (64 cols).
//      Q,K stored natural [row][dim]; V stored transposed [dim][key].
//  P2: per-head attention, head = wave id. S^T = K_h @ Q_h^T (32x32x16,
//      swapped so col=q, row=key). Softmax = 32-reg local + shfl_xor(32).
//      P->PV A-frags rebuilt in-register (pack pairs + xor32 exchange).
//      O_h = P @ V_h (32x32x16, B from V^T). O aliases the K buffer
//      (each wave touches only its own head's 16 columns).
//  P3: X += O@Wo + bo; X kept as bf16 hi/lo pair (residual master).
//  Final: query = X@Wq + bq -> global fp32.
// LDS: 6*[64][136]u16 + 2*[128][72]u16 = 138.0 KB -> 1 block/CU.
// MFMA fragment layouts (gfx950, per guide m89/m91/m74/m101/m214):
//  16x16x32: A row=lane&15,k=(lane>>4)*8+j; B col=lane&15,k=(lane>>4)*8+j;
//            C col=lane&15,row=(lane>>4)*4+reg.
//  32x32x16: A row=lane&31,k=(lane>>5)*8+j; B col=lane&31,k=(lane>>5)*8+j;
//            C col=lane&31,row=(reg&3)+8*(reg>>2)+4*(lane>>5).
// ---------------------------------------------------------------------------
__global__ __launch_bounds__(512, 1) void gat_query_mfma(
    const float* __restrict__ hin,
    const unsigned short* __restrict__ gwt_hi,
    const unsigned short* __restrict__ gwt_lo,
    const float* __restrict__ gbq, const float* __restrict__ gbk,
    const float* __restrict__ gbv, const float* __restrict__ gbo,
    const float* __restrict__ bq,
    float* __restrict__ query)
{
  __shared__ unsigned short XH[64 * XP], XL[64 * XP];
  __shared__ unsigned short QH[64 * XP], QL[64 * XP];
  __shared__ unsigned short KH[64 * XP], KL[64 * XP];   // doubles as O hi/lo
  __shared__ unsigned short VTH[128 * VP], VTL[128 * VP];

  const int b    = blockIdx.x;
  const int tid  = threadIdx.x;
  const int wid  = tid >> 6;
  const int lane = tid & 63;
  const int l15  = lane & 15;
  const int quad = lane >> 4;
  const int col  = lane & 31;
  const int hi32 = lane >> 5;

  // load + split X
  for (int idx = tid; idx < NQ * EE; idx += 512) {
    const float v = hin[(size_t)b * NQ * EE + idx];
    const int r = idx >> 7, c = idx & 127;
    const unsigned short h = f2bf(v);
    XH[r * XP + c] = h;
    XL[r * XP + c] = f2bf(v - bf2f(h));
  }
  __syncthreads();

  const int mt = wid >> 1, nh = wid & 1;
  const int r0 = mt * 16;

  for (int l = 0; l < NL; ++l) {
    // ---------------- P1: Q,K,V projections ----------------
    {
      bf16x8 axh[4], axl[4];
      #pragma unroll
      for (int k4 = 0; k4 < 4; ++k4) {
        axh[k4] = ld8(&XH[(r0 + l15) * XP + k4 * 32 + quad * 8]);
        axl[k4] = ld8(&XL[(r0 + l15) * XP + k4 * 32 + quad * 8]);
      }
      #pragma unroll
      for (int m = 0; m < 3; ++m) {
        const unsigned short* WH = gwt_hi + (size_t)(l * 4 + m) * 16384;
        const unsigned short* WL = gwt_lo + (size_t)(l * 4 + m) * 16384;
        const float* bias = (m == 0 ? gbq : (m == 1 ? gbk : gbv)) + l * EE;
        #pragma unroll
        for (int ntl = 0; ntl < 4; ++ntl) {
          const int n = (nh * 4 + ntl) * 16 + l15;
          f32x4 acc = (f32x4){0.f, 0.f, 0.f, 0.f};
          #pragma unroll
          for (int k4 = 0; k4 < 4; ++k4) {
            const int k0 = k4 * 32 + quad * 8;
            const bf16x8 bh = ld8(&WH[n * EE + k0]);
            const bf16x8 bl = ld8(&WL[n * EE + k0]);
            acc = __builtin_amdgcn_mfma_f32_16x16x32_bf16(axh[k4], bh, acc, 0, 0, 0);
            acc = __builtin_amdgcn_mfma_f32_16x16x32_bf16(axh[k4], bl, acc, 0, 0, 0);
            acc = __builtin_amdgcn_mfma_f32_16x16x32_bf16(axl[k4], bh, acc, 0, 0, 0);
          }
          const float bv = bias[n];
          if (m == 2) {
            // V transposed: pack 4 consecutive key-rows -> one b64 store
            u16x4 hv, lv;
            #pragma unroll
            for (int r = 0; r < 4; ++r) {
              const float v = acc[r] + bv;
              const unsigned short h = f2bf(v);
              hv[r] = h;
              lv[r] = f2bf(v - bf2f(h));
            }
            *(u16x4*)&VTH[n * VP + r0 + quad * 4] = hv;
            *(u16x4*)&VTL[n * VP + r0 + quad * 4] = lv;
          } else {
            unsigned short* DH = m ? KH : QH;
            unsigned short* DL = m ? KL : QL;
            #pragma unroll
            for (int r = 0; r < 4; ++r) {
              const int crow = r0 + quad * 4 + r;
              const float v = acc[r] + bv;
              const unsigned short h = f2bf(v);
              DH[crow * XP + n] = h;
              DL[crow * XP + n] = f2bf(v - bf2f(h));
            }
          }
        }
      }
    }
    __syncthreads();

    // ---------------- P2: attention, head = wid ----------------
    {
      const int hwid = wid;
      const int hb = hwid * 16 + hi32 * 8;
      bf16x8 akh[2], akl[2], qbh[2], qbl[2];
      #pragma unroll
      for (int t = 0; t < 2; ++t) {
        akh[t] = ld8(&KH[(t * 32 + col) * XP + hb]);
        akl[t] = ld8(&KL[(t * 32 + col) * XP + hb]);
        qbh[t] = ld8(&QH[(t * 32 + col) * XP + hb]);
        qbl[t] = ld8(&QL[(t * 32 + col) * XP + hb]);
      }

      bf16x8 pah[2][4], pal[2][4];   // PV A-frags [qt][ks]
      #pragma unroll
      for (int qt = 0; qt < 2; ++qt) {
        // S^T tiles for this qt: col=q, row=key
        f32x16 sAcc[2];
        #pragma unroll
        for (int kt = 0; kt < 2; ++kt) {
          #pragma unroll
          for (int i = 0; i < 16; ++i) sAcc[kt][i] = 0.f;
          sAcc[kt] = __builtin_amdgcn_mfma_f32_32x32x16_bf16(akh[kt], qbh[qt], sAcc[kt], 0, 0, 0);
          sAcc[kt] = __builtin_amdgcn_mfma_f32_32x32x16_bf16(akh[kt], qbl[qt], sAcc[kt], 0, 0, 0);
          sAcc[kt] = __builtin_amdgcn_mfma_f32_32x32x16_bf16(akl[kt], qbh[qt], sAcc[kt], 0, 0, 0);
        }
        // softmax over 64 keys: 32 local values + partner lane (^32)
        float p[2][16];
        float mx = -INFINITY;
        #pragma unroll
        for (int kt = 0; kt < 2; ++kt)
          #pragma unroll
          for (int r = 0; r < 16; ++r) {
            p[kt][r] = sAcc[kt][r] * 0.25f;
            mx = fmaxf(mx, p[kt][r]);
          }
        mx = fmaxf(mx, __shfl_xor(mx, 32));
        float sum = 0.f;
        #pragma unroll
        for (int kt = 0; kt < 2; ++kt)
          #pragma unroll
          for (int r = 0; r < 16; ++r) {
            p[kt][r] = exp2f((p[kt][r] - mx) * 1.4426950408889634f);
            sum += p[kt][r];
          }
        sum += __shfl_xor(sum, 32);
        const float inv = 1.f / sum;

        // split+pack: word w holds keys (2w,2w+1) of lane's own key set
        // (own keys within kt-tile: {t + 8g + 4*hi32}, regs r = t + 4g)
        unsigned pkh[2][8], pkl[2][8], swh[2][8], swl[2][8];
        #pragma unroll
        for (int kt = 0; kt < 2; ++kt)
          #pragma unroll
          for (int w = 0; w < 8; ++w) {
            const float v0 = p[kt][w * 2]     * inv;
            const float v1 = p[kt][w * 2 + 1] * inv;
            const unsigned short h0 = f2bf(v0);
            const unsigned short l0 = f2bf(v0 - bf2f(h0));
            const unsigned short h1 = f2bf(v1);
            const unsigned short l1 = f2bf(v1 - bf2f(h1));
            pkh[kt][w] = (unsigned)h0 | ((unsigned)h1 << 16);
            pkl[kt][w] = (unsigned)l0 | ((unsigned)l1 << 16);
            swh[kt][w] = (unsigned)__shfl_xor((int)pkh[kt][w], 32);
            swl[kt][w] = (unsigned)__shfl_xor((int)pkl[kt][w], 32);
          }
        // assemble A-frags: frag(ks) = att[q][ks*16 + hi32*8 + 0..7]
        const bool top = (hi32 != 0);
        #pragma unroll
        for (int ks = 0; ks < 4; ++ks) {
          const int kt = ks >> 1, hf = ks & 1;
          u32x4 wh, wl;
          wh[0] = top ? swh[kt][4 * hf + 2] : pkh[kt][4 * hf + 0];
          wh[1] = top ? swh[kt][4 * hf + 3] : pkh[kt][4 * hf + 1];
          wh[2] = top ? pkh[kt][4 * hf + 2] : swh[kt][4 * hf + 0];
          wh[3] = top ? pkh[kt][4 * hf + 3] : swh[kt][4 * hf + 1];
          wl[0] = top ? swl[kt][4 * hf + 2] : pkl[kt][4 * hf + 0];
          wl[1] = top ? swl[kt][4 * hf + 3] : pkl[kt][4 * hf + 1];
          wl[2] = top ? pkl[kt][4 * hf + 2] : swl[kt][4 * hf + 0];
          wl[3] = top ? pkl[kt][4 * hf + 3] : swl[kt][4 * hf + 1];
          pah[qt][ks] = __builtin_bit_cast(bf16x8, wh);
          pal[qt][ks] = __builtin_bit_cast(bf16x8, wl);
        }
      }

      // O_h = P @ V_h : B-frags from V^T (cols >=16 duplicate, discarded)
      bf16x8 bvh[4], bvl[4];
      const int vrow = hwid * 16 + (col & 15);
      #pragma unroll
      for (int ks = 0; ks < 4; ++ks) {
        bvh[ks] = ld8(&VTH[vrow * VP + ks * 16 + hi32 * 8]);
        bvl[ks] = ld8(&VTL[vrow * VP + ks * 16 + hi32 * 8]);
      }
      f32x16 accO[2];
      #pragma unroll
      for (int qt = 0; qt < 2; ++qt) {
        #pragma unroll
        for (int i = 0; i < 16; ++i) accO[qt][i] = 0.f;
        #pragma unroll
        for (int ks = 0; ks < 4; ++ks) {
          accO[qt] = __builtin_amdgcn_mfma_f32_32x32x16_bf16(pah[qt][ks], bvh[ks], accO[qt], 0, 0, 0);
          accO[qt] = __builtin_amdgcn_mfma_f32_32x32x16_bf16(pah[qt][ks], bvl[ks], accO[qt], 0, 0, 0);
          accO[qt] = __builtin_amdgcn_mfma_f32_32x32x16_bf16(pal[qt][ks], bvh[ks], accO[qt], 0, 0, 0);
        }
      }
      // store O into K-alias (own head's 16 columns only)
      if (col < 16) {
        #pragma unroll
        for (int qt = 0; qt < 2; ++qt)
          #pragma unroll
          for (int r = 0; r < 16; ++r) {
            const int qrow = qt * 32 + (r & 3) + 8 * (r >> 2) + 4 * hi32;
            const float v = accO[qt][r];
            const unsigned short h = f2bf(v);
            KH[qrow * XP + hwid * 16 + col] = h;
            KL[qrow * XP + hwid * 16 + col] = f2bf(v - bf2f(h));
          }
      }
    }
    __syncthreads();

    // ---------------- P3: X += O@Wo + bo ----------------
    {
      bf16x8 aoh[4], aol[4];
      #pragma unroll
      for (int k4 = 0; k4 < 4; ++k4) {
        aoh[k4] = ld8(&KH[(r0 + l15) * XP + k4 * 32 + quad * 8]);
        aol[k4] = ld8(&KL[(r0 + l15) * XP + k4 * 32 + quad * 8]);
      }
      const unsigned short* WH = gwt_hi + (size_t)(l * 4 + 3) * 16384;
      const unsigned short* WL = gwt_lo + (size_t)(l * 4 + 3) * 16384;
      #pragma unroll
      for (int ntl = 0; ntl < 4; ++ntl) {
        const int n = (nh * 4 + ntl) * 16 + l15;
        f32x4 acc = (f32x4){0.f, 0.f, 0.f, 0.f};
        #pragma unroll
        for (int k4 = 0; k4 < 4; ++k4) {
          const int k0 = k4 * 32 + quad * 8;
          const bf16x8 bh = ld8(&WH[n * EE + k0]);
          const bf16x8 bl = ld8(&WL[n * EE + k0]);
          acc = __builtin_amdgcn_mfma_f32_16x16x32_bf16(aoh[k4], bh, acc, 0, 0, 0);
          acc = __builtin_amdgcn_mfma_f32_16x16x32_bf16(aoh[k4], bl, acc, 0, 0, 0);
          acc = __builtin_amdgcn_mfma_f32_16x16x32_bf16(aol[k4], bh, acc, 0, 0, 0);
        }
        const float bv = gbo[l * EE + n];
        #pragma unroll
        for (int r = 0; r < 4; ++r) {
          const int crow = r0 + quad * 4 + r;
          const float xo = bf2f(XH[crow * XP + n]) + bf2f(XL[crow * XP + n]);
          const float v = xo + acc[r] + bv;
          const unsigned short h = f2bf(v);
          XH[crow * XP + n] = h;
          XL[crow * XP + n] = f2bf(v - bf2f(h));
        }
      }
    }
    __syncthreads();
  }

  // ---------------- final query projection ----------------
  {
    bf16x8 axh[4], axl[4];
    #pragma unroll
    for (int k4 = 0; k4 < 4; ++k4) {
      axh[k4] = ld8(&XH[(r0 + l15) * XP + k4 * 32 + quad * 8]);
      axl[k4] = ld8(&XL[(r0 + l15) * XP + k4 * 32 + quad * 8]);
    }
    const unsigned short* WH = gwt_hi + (size_t)12 * 16384;
    const unsigned short* WL = gwt_lo + (size_t)12 * 16384;
    #pragma unroll
    for (int ntl = 0; ntl < 4; ++ntl) {
      const int n = (nh * 4 + ntl) * 16 + l15;
      f32x4 acc = (f32x4){0.f, 0.f, 0.f, 0.f};
      #pragma unroll
      for (int k4 = 0; k4 < 4; ++k4) {
        const int k0 = k4 * 32 + quad * 8;
        const bf16x8 bh = ld8(&WH[n * EE + k0]);
        const bf16x8 bl = ld8(&WL[n * EE + k0]);
        acc = __builtin_amdgcn_mfma_f32_16x16x32_bf16(axh[k4], bh, acc, 0, 0, 0);
        acc = __builtin_amdgcn_mfma_f32_16x16x32_bf16(axh[k4], bl, acc, 0, 0, 0);
        acc = __builtin_amdgcn_mfma_f32_16x16x32_bf16(axl[k4], bh, acc, 0, 0, 0);
      }
      const float bv = bq[n];
      #pragma unroll
      for (int r = 0; r < 4; ++r) {
        const int crow = r0 + quad * 4 + r;
        query[((size_t)b * NQ + crow) * EE + n] = acc[r] + bv;
      }
    }
  }
}

// ---------------------------------------------------------------------------
// Kernel 2: MFMA compat. One block per (candidate-chunk, batch).  (unchanged)
// ---------------------------------------------------------------------------
__global__ __launch_bounds__(256, 2) void compat_mfma_kernel(
    const float* __restrict__ cin,
    const float* __restrict__ query,
    const unsigned char* __restrict__ mask,
    const unsigned short* __restrict__ wkt_hi,
    const unsigned short* __restrict__ wkt_lo,
    const float* __restrict__ bk,
    float* __restrict__ compat_out,
    float* __restrict__ compts)
{
  __shared__ unsigned short Khi[128 * KP];
  __shared__ unsigned short Klo[128 * KP];
  __shared__ float colsum[128];

  const int ch   = blockIdx.x;
  const int b    = blockIdx.y;
  const int tid  = threadIdx.x;
  const int wave = tid >> 6;
  const int lane = tid & 63;
  const int l15  = lane & 15;
  const int quad = lane >> 4;

  if (tid < 128) colsum[tid] = 0.f;

  // ---------------- Phase A: key projection ----------------
  {
    f32x4 acc[2][8];
    #pragma unroll
    for (int mt = 0; mt < 2; ++mt)
      #pragma unroll
      for (int nt = 0; nt < 8; ++nt)
        acc[mt][nt] = (f32x4){0.f, 0.f, 0.f, 0.f};

    #pragma unroll
    for (int k4 = 0; k4 < 4; ++k4) {
      const int k0 = k4 * 32 + quad * 8;
      bf16x8 ahi[2], alo[2];
      #pragma unroll
      for (int mt = 0; mt < 2; ++mt) {
        int grow = ch * 128 + (wave * 2 + mt) * 16 + l15;
        if (grow > NCC - 1) grow = NCC - 1;
        const float* src = &cin[((size_t)b * NCC + grow) * EE + k0];
        const float4 x0 = *(const float4*)&src[0];
        const float4 x1 = *(const float4*)&src[4];
        float xv[8] = {x0.x, x0.y, x0.z, x0.w, x1.x, x1.y, x1.z, x1.w};
        u16x8 h, lo;
        #pragma unroll
        for (int j = 0; j < 8; ++j) {
          unsigned short hb = f2bf(xv[j]);
          h[j] = hb;
          lo[j] = f2bf(xv[j] - bf2f(hb));
        }
        ahi[mt] = __builtin_bit_cast(bf16x8, h);
        alo[mt] = __builtin_bit_cast(bf16x8, lo);
      }
      #pragma unroll
      for (int nt = 0; nt < 8; ++nt) {
        const int n = nt * 16 + l15;
        const bf16x8 bhi = __builtin_bit_cast(bf16x8, *(const u16x8*)&wkt_hi[n * EE + k0]);
        const bf16x8 blo = __builtin_bit_cast(bf16x8, *(const u16x8*)&wkt_lo[n * EE + k0]);
        #pragma unroll
        for (int mt = 0; mt < 2; ++mt) {
          acc[mt][nt] = __builtin_amdgcn_mfma_f32_16x16x32_bf16(ahi[mt], bhi, acc[mt][nt], 0, 0, 0);
          acc[mt][nt] = __builtin_amdgcn_mfma_f32_16x16x32_bf16(ahi[mt], blo, acc[mt][nt], 0, 0, 0);
          acc[mt][nt] = __builtin_amdgcn_mfma_f32_16x16x32_bf16(alo[mt], bhi, acc[mt][nt], 0, 0, 0);
        }
      }
    }

    #pragma unroll
    for (int nt = 0; nt < 8; ++nt) {
      const int n = nt * 16 + l15;
      const float bkv = bk[n];
      #pragma unroll
      for (int mt = 0; mt < 2; ++mt) {
        #pragma unroll
        for (int r = 0; r < 4; ++r) {
          const int crow = (wave * 2 + mt) * 16 + quad * 4 + r;
          const float v = acc[mt][nt][r] + bkv;
          const unsigned short hb = f2bf(v);
          Khi[crow * KP + n] = hb;
          Klo[crow * KP + n] = f2bf(v - bf2f(hb));
        }
      }
    }
  }
  __syncthreads();

  // ---------------- Phase B: S = Q @ K^T ----------------
  {
    bf16x8 qhi[4], qlo[4];
    #pragma unroll
    for (int k4 = 0; k4 < 4; ++k4) {
      const float* src = &query[((size_t)b * NQ + wave * 16 + l15) * EE + k4 * 32 + quad * 8];
      const float4 x0 = *(const float4*)&src[0];
      const float4 x1 = *(const float4*)&src[4];
      float xv[8] = {x0.x, x0.y, x0.z, x0.w, x1.x, x1.y, x1.z, x1.w};
      u16x8 h, lo;
      #pragma unroll
      for (int j = 0; j < 8; ++j) {
        unsigned short hb = f2bf(xv[j]);
        h[j] = hb;
        lo[j] = f2bf(xv[j] - bf2f(hb));
      }
      qhi[k4] = __builtin_bit_cast(bf16x8, h);
      qlo[k4] = __builtin_bit_cast(bf16x8, lo);
    }

    f32x4 acc[8];
    #pragma unroll
    for (int nt = 0; nt < 8; ++nt) acc[nt] = (f32x4){0.f, 0.f, 0.f, 0.f};

    #pragma unroll
    for (int k4 = 0; k4 < 4; ++k4) {
      const int k0 = k4 * 32 + quad * 8;
      #pragma unroll
      for (int nt = 0; nt < 8; ++nt) {
        const int crow = nt * 16 + l15;
        const bf16x8 khf = __builtin_bit_cast(bf16x8, *(const u16x8*)&Khi[crow * KP + k0]);
        const bf16x8 klf = __builtin_bit_cast(bf16x8, *(const u16x8*)&Klo[crow * KP + k0]);
        acc[nt] = __builtin_amdgcn_mfma_f32_16x16x32_bf16(qhi[k4], khf, acc[nt], 0, 0, 0);
        acc[nt] = __builtin_amdgcn_mfma_f32_16x16x32_bf16(qhi[k4], klf, acc[nt], 0, 0, 0);
        acc[nt] = __builtin_amdgcn_mfma_f32_16x16x32_bf16(qlo[k4], khf, acc[nt], 0, 0, 0);
      }
    }

    #pragma unroll
    for (int nt = 0; nt < 8; ++nt) {
      const int jloc  = nt * 16 + l15;
      const int jglob = ch * 128 + jloc;
      const bool jok  = (jglob < NCC);
      float s4 = 0.f;
      #pragma unroll
      for (int r = 0; r < 4; ++r) {
        const int q = wave * 16 + quad * 4 + r;
        float v = tanhf(acc[nt][r] * 0.25f) * 10.f;
        if (jok) {
          if (mask[((size_t)b * NQ + q) * (NCC + 1) + 1 + jglob]) v = -INFINITY;
          compat_out[((size_t)b * NQ + q) * NCC + jglob] = v;
        }
        s4 += v;
      }
      s4 += __shfl_xor(s4, 16);
      s4 += __shfl_xor(s4, 32);
      if (lane < 16 && jok) atomicAdd(&colsum[jloc], s4);
    }
  }
  __syncthreads();

  if (tid < 128) {
    const int jglob = ch * 128 + tid;
    if (jglob < NCC)
      compts[(size_t)b * 1024 + jglob] = colsum[tid] * (1.0f / (float)NQ);
  }
}

// ---------------------------------------------------------------------------
// Kernel 3: per-batch argmax over compts with cluster masking. (unchanged)
// ---------------------------------------------------------------------------
__global__ __launch_bounds__(256) void argmax_kernel(
    const float* __restrict__ compts,
    const unsigned char* __restrict__ clusters,
    const int* __restrict__ depot_id,
    float* __restrict__ out)
{
  __shared__ float redv[256];
  __shared__ int   redi[256];
  const int b   = blockIdx.x;
  const int tid = threadIdx.x;
  const int dep = depot_id[0];
  float bestv = -INFINITY;
  int   besti = 0x7fffffff;
  for (int j = tid; j < NCC; j += 256) {
    float t = compts[(size_t)b * 1024 + j];
    if (clusters[((size_t)b * DD + dep) * NCC + j]) t = -INFINITY;
    if (t > bestv || (t == bestv && j < besti)) { bestv = t; besti = j; }
  }
  redv[tid] = bestv; redi[tid] = besti;
  __syncthreads();
  if (tid == 0) {
    float bv = redv[0]; int bi = redi[0];
    for (int t = 1; t < 256; ++t) {
      if (redv[t] > bv || (redv[t] == bv && redi[t] < bi)) {
        bv = redv[t]; bi = redi[t];
      }
    }
    out[b] = (float)bi;
  }
}

// ---------------------------------------------------------------------------
extern "C" void kernel_launch(void* const* d_in, const int* in_sizes, int n_in,
                              void* d_out, int out_size, void* d_ws, size_t ws_size,
                              hipStream_t stream) {
  const float* hin      = (const float*)d_in[0];
  const float* cin      = (const float*)d_in[1];
  const unsigned char* mask     = (const unsigned char*)d_in[2];
  const unsigned char* clusters = (const unsigned char*)d_in[3];
  const int*   depot    = (const int*)d_in[4];
  const float* gWq = (const float*)d_in[5];
  const float* gbq = (const float*)d_in[6];
  const float* gWk = (const float*)d_in[7];
  const float* gbk = (const float*)d_in[8];
  const float* gWv = (const float*)d_in[9];
  const float* gbv = (const float*)d_in[10];
  const float* gWo = (const float*)d_in[11];
  const float* gbo = (const float*)d_in[12];
  const float* Wq  = (const float*)d_in[13];
  const float* bq  = (const float*)d_in[14];
  const float* Wk  = (const float*)d_in[15];
  const float* bk  = (const float*)d_in[16];
  float* out   = (float*)d_out;
  float* compat_out = out + NB;

  // ws layout: query f32 (16 MiB) | compts (2 MiB) | gwt_hi (448 KiB) | gwt_lo (448 KiB)
  float*          query  = (float*)d_ws;
  float*          compts = (float*)((char*)d_ws + (size_t)NB * NQ * EE * 4);
  unsigned short* gwt_hi = (unsigned short*)((char*)compts + (size_t)NB * 1024 * 4);
  unsigned short* gwt_lo = gwt_hi + (size_t)14 * 16384;
  unsigned short* wkt_hi = gwt_hi + (size_t)13 * 16384;   // mat 13 = final Wk
  unsigned short* wkt_lo = gwt_lo + (size_t)13 * 16384;

  wprep_kernel<<<896, 256, 0, stream>>>(gWq, gWk, gWv, gWo, Wq, Wk, gwt_hi, gwt_lo);
  gat_query_mfma<<<NB, 512, 0, stream>>>(hin, gwt_hi, gwt_lo,
                                         gbq, gbk, gbv, gbo, bq, query);
  compat_mfma_kernel<<<dim3(8, NB), 256, 0, stream>>>(
      cin, query, mask, wkt_hi, wkt_lo, bk, compat_out, compts);
  argmax_kernel<<<NB, 256, 0, stream>>>(compts, clusters, depot, out);
}